// Round 18
// baseline (62.763 us; speedup 1.0000x reference)
//
#include <hip/hip_runtime.h>
#include <hip/hip_bf16.h>

#define HEADS 4
#define DIMH  32
#define HID   128
#define DIM   128
#define NSP   4096
// 10 * log2(e); folded into the per-channel factor f = scq*sck*QSCALE_LOG2E.
#define QSCALE_LOG2E 14.426950408889634f

typedef __attribute__((ext_vector_type(4)))  float f32x4;
typedef __attribute__((ext_vector_type(16))) float f32x16;
typedef __attribute__((ext_vector_type(8)))  short s16x8;

__device__ __forceinline__ unsigned cvtpk_bf16(float a, float b) {
  unsigned d;
  asm("v_cvt_pk_bf16_f32 %0, %1, %2" : "=v"(d) : "v"(a), "v"(b));
  return d;
}

// ---------------- convert+transpose x,y fp32 [b][c][n] -> bf16 [b*n][c] ----------------
__global__ __launch_bounds__(256) void k_cvt(const float* __restrict__ x,
                                             const float* __restrict__ y,
                                             __hip_bfloat16* __restrict__ xt,
                                             __hip_bfloat16* __restrict__ yt) {
  int bid = blockIdx.x;          // 2 tensor * 2 b * 64 ntiles
  int t = bid >> 7, rem = bid & 127;
  int b = rem >> 6, nt = rem & 63;
  int n0 = nt * 64;
  const float* src = (t ? y : x) + (size_t)b * DIM * NSP;
  __hip_bfloat16* dst = (t ? yt : xt) + (size_t)b * NSP * DIM;

  __shared__ alignas(16) __hip_bfloat16 tile[64 * 136];
  int n = threadIdx.x & 63, c0 = threadIdx.x >> 6;   // c0 0..3
  const float* sp = src + n0 + n;
#pragma unroll
  for (int cc = 0; cc < 32; ++cc) {
    int c = cc * 4 + c0;
    tile[n * 136 + c] = __float2bfloat16(sp[(size_t)c * NSP]);
  }
  __syncthreads();
  int rrow = threadIdx.x >> 2, cb = (threadIdx.x & 3) * 32;
  __hip_bfloat16* op = dst + (size_t)(n0 + rrow) * DIM + cb;
  const __hip_bfloat16* ip = tile + rrow * 136 + cb;
#pragma unroll
  for (int k = 0; k < 4; ++k)
    *(s16x8*)(op + k * 8) = *(const s16x8*)(ip + k * 8);
}

// ---------------- QKV GEMM on MFMA ----------------
// orows 0..127 = Q (fp32 out), 128..255 = K (bf16), 256..383 = V (bf16).
// Sum-of-squares: deterministic per-wave partials into ssp[512][64] (no atomics).
__global__ __launch_bounds__(256, 4) void k_qkvm(const __hip_bfloat16* __restrict__ xt,
                                                 const __hip_bfloat16* __restrict__ yt,
                                                 const float* __restrict__ w,
                                                 float* __restrict__ ssp,
                                                 float* __restrict__ Qf,
                                                 __hip_bfloat16* __restrict__ Kr,
                                                 __hip_bfloat16* __restrict__ Vb) {
  int xcd = blockIdx.x & 7;
  int r = blockIdx.x >> 3;        // 0..47
  int ot = r >> 2;                // 0..11
  int nts = r & 3;
  int tile = xcd * 4 + nts;       // n-tile 0..31
  int n0 = tile * 256;
  int lane = threadIdx.x & 63, wave = threadIdx.x >> 6;
  int l31 = lane & 31, hi = lane >> 5;
  int orow = ot * 32 + l31;

  s16x8 wf[8];
  const float* wr = w + orow * DIM + hi * 8;
#pragma unroll
  for (int k = 0; k < 8; ++k) {
    f32x4 a = *(const f32x4*)(wr + k * 16);
    f32x4 b2 = *(const f32x4*)(wr + k * 16 + 4);
    union { unsigned u[4]; s16x8 v; } p;
    p.u[0] = cvtpk_bf16(a[0], a[1]);
    p.u[1] = cvtpk_bf16(a[2], a[3]);
    p.u[2] = cvtpk_bf16(b2[0], b2[1]);
    p.u[3] = cvtpk_bf16(b2[2], b2[3]);
    wf[k] = p.v;
  }

  const __hip_bfloat16* src = (ot < 4 ? xt : yt);
  int nw = n0 + wave * 64;
  f32x16 acc0 = {}, acc1 = {};
#pragma unroll
  for (int k = 0; k < 8; ++k) {
    s16x8 b0 = *(const s16x8*)(src + (size_t)(nw + l31) * DIM + k * 16 + hi * 8);
    s16x8 b1 = *(const s16x8*)(src + (size_t)(nw + 32 + l31) * DIM + k * 16 + hi * 8);
    acc0 = __builtin_amdgcn_mfma_f32_32x32x16_bf16(wf[k], b0, acc0, 0, 0, 0);
    acc1 = __builtin_amdgcn_mfma_f32_32x32x16_bf16(wf[k], b1, acc1, 0, 0, 0);
  }

  int b = nw >> 12;
  if (ot < 8) {
    int h = ot & 3;
    if (ot < 4) {
#pragma unroll
      for (int nt = 0; nt < 2; ++nt) {
        int np = (nw + nt * 32 + l31) & 4095;
        float* base = Qf + ((size_t)((b * HEADS + h) * NSP + np)) * DIMH;
        const f32x16& A = nt ? acc1 : acc0;
#pragma unroll
        for (int m = 0; m < 4; ++m) {
          f32x4 v = { A[4 * m], A[4 * m + 1], A[4 * m + 2], A[4 * m + 3] };
          *(f32x4*)(base + 8 * m + 4 * hi) = v;
        }
      }
    } else {
#pragma unroll
      for (int nt = 0; nt < 2; ++nt) {
        int np = (nw + nt * 32 + l31) & 4095;
        __hip_bfloat16* base = Kr + ((size_t)((b * HEADS + h) * NSP + np)) * DIMH;
        const f32x16& A = nt ? acc1 : acc0;
#pragma unroll
        for (int m = 0; m < 4; ++m) {
          uint2 p2;
          p2.x = cvtpk_bf16(A[4 * m], A[4 * m + 1]);
          p2.y = cvtpk_bf16(A[4 * m + 2], A[4 * m + 3]);
          *(uint2*)(base + 8 * m + 4 * hi) = p2;
        }
      }
    }
    float p[16];
#pragma unroll
    for (int r2 = 0; r2 < 16; ++r2) p[r2] = acc0[r2] * acc0[r2] + acc1[r2] * acc1[r2];
#pragma unroll
    for (int r2 = 0; r2 < 16; ++r2) {
#pragma unroll
      for (int m2 = 1; m2 < 32; m2 <<= 1) p[r2] += __shfl_xor(p[r2], m2);
    }
    if (l31 == 0) {
      int t = (ot < 4 ? 0 : 1);
      int widx = (tile & 15) * 4 + wave;              // 0..63
      int rbase = (t * 2 + b) * 128 + h * 32;
#pragma unroll
      for (int r2 = 0; r2 < 16; ++r2) {
        int row = (r2 & 3) + 8 * (r2 >> 2) + 4 * hi;
        ssp[(size_t)(rbase + row) * 64 + widx] = p[r2];
      }
    }
  } else {
    int h = ot - 8;
#pragma unroll
    for (int nt = 0; nt < 2; ++nt) {
      int np = (nw + nt * 32 + l31) & 4095;
      const f32x16& A = nt ? acc1 : acc0;
#pragma unroll
      for (int r2 = 0; r2 < 16; ++r2) {
        int d = (r2 & 3) + 8 * (r2 >> 2) + 4 * hi;
        Vb[((size_t)((b * HEADS + h) * DIMH + d)) * NSP + np] = __float2bfloat16(A[r2]);
      }
    }
  }
}

// ---------------- flash attention: wave-private self-staged K/V, ZERO main-loop barriers ----------------
__device__ __forceinline__ void glds16(const __hip_bfloat16* g, __hip_bfloat16* l) {
  __builtin_amdgcn_global_load_lds(
      (const __attribute__((address_space(1))) unsigned int*)(const void*)g,
      (__attribute__((address_space(3))) unsigned int*)(void*)l, 16, 0, 0);
}

// One 32(q-rows) x 32(j) subtile from a wave-private 32-j LDS tile.
// Swizzle phase = (row + row>>2) & 3 on 64B rows: lanes l,l+4,l+8,l+12 hit 4 distinct
// slots; only l<->l+16 aliases -> free 2-way (m136). Same phase for K and V tiles.
__device__ __forceinline__ void attn_sub3(const __hip_bfloat16* kbase,
                                          const __hip_bfloat16* vbase,
                                          int l31, int hi,
                                          s16x8 qb0, s16x8 qb1,
                                          f32x16& O, float& lsum) {
  int rx = (l31 + (l31 >> 2)) & 3;
  const __hip_bfloat16* krow = kbase + l31 * DIMH;
  s16x8 kf0 = *(const s16x8*)(krow + (((hi) ^ rx) << 3));
  s16x8 kf1 = *(const s16x8*)(krow + (((2 + hi) ^ rx) << 3));
  f32x16 z = {};
  __builtin_amdgcn_s_setprio(1);
  f32x16 sv = __builtin_amdgcn_mfma_f32_32x32x16_bf16(kf0, qb0, z, 0, 0, 0);
  sv        = __builtin_amdgcn_mfma_f32_32x32x16_bf16(kf1, qb1, sv, 0, 0, 0);
  __builtin_amdgcn_s_setprio(0);
  float p[16];
#pragma unroll
  for (int r = 0; r < 16; ++r) p[r] = __builtin_amdgcn_exp2f(sv[r]);
  float t0 = 0.f, t1 = 0.f;
#pragma unroll
  for (int r = 0; r < 16; r += 2) { t0 += p[r]; t1 += p[r + 1]; }
  lsum += t0 + t1;
  unsigned wA[4], wB[4];
#pragma unroll
  for (int m = 0; m < 4; ++m) {
    wA[m] = cvtpk_bf16(p[4 * m], p[4 * m + 1]);
    wB[m] = cvtpk_bf16(p[4 * m + 2], p[4 * m + 3]);
  }
  const __hip_bfloat16* vrow = vbase + l31 * 32;
#define PV_CHUNK(c2, vfrag)                                                    \
  {                                                                            \
    unsigned a0 = wA[2 * (c2)], a1 = wA[2 * (c2) + 1];                         \
    unsigned b0 = wB[2 * (c2)], b1 = wB[2 * (c2) + 1];                         \
    asm("v_permlane32_swap_b32 %0, %1" : "+v"(a0), "+v"(a1));                  \
    asm("v_permlane32_swap_b32 %0, %1" : "+v"(b0), "+v"(b1));                  \
    union { unsigned u[4]; s16x8 v; } pa;                                      \
    pa.u[0] = a0; pa.u[1] = b0; pa.u[2] = a1; pa.u[3] = b1;                    \
    __builtin_amdgcn_s_setprio(1);                                             \
    O = __builtin_amdgcn_mfma_f32_32x32x16_bf16(pa.v, vfrag, O, 0, 0, 0);      \
    __builtin_amdgcn_s_setprio(0);                                             \
  }
#pragma unroll
  for (int c2 = 0; c2 < 2; ++c2) {
    s16x8 vf = *(const s16x8*)(vrow + (((c2 * 2 + hi) ^ rx) << 3));
    PV_CHUNK(c2, vf);
  }
#undef PV_CHUNK
}

// block = 4 waves (32 q-rows, 4-way j split), grid = 1024 (8 bh XCD-local x 128 qt).
// Each wave self-stages private 32-j K/V tiles (2+2 glds16), double-buffered,
// counted vmcnt(4) -> NO barriers in the main loop. fsc reduction fused in prologue.
__global__ __launch_bounds__(256, 4) void k_attn(const float* __restrict__ Qf,
                                                 const __hip_bfloat16* __restrict__ Kt,
                                                 const __hip_bfloat16* __restrict__ Vb,
                                                 const float* __restrict__ ssp,
                                                 __hip_bfloat16* __restrict__ Otb) {
  int bh = blockIdx.x & 7, qt = blockIdx.x >> 3;   // 8 bh x 128 qt
  int tid = threadIdx.x, lane = tid & 63, wave = tid >> 6;  // wave = jq
  int l31 = lane & 31, hi = lane >> 5;
  int i0 = qt * 32;
  int jbase = wave * 1024;
  int b = bh >> 2, h = bh & 3;

  __shared__ alignas(16) char smem[32768];   // K[4w][2buf][2KB] + V[4w][2buf][2KB]; Olds aliased
  __shared__ float Llds[4][64];
  __shared__ float redl[64];
  __shared__ float fscl[32];
  __hip_bfloat16* KsB = (__hip_bfloat16*)smem;          // elems; wave stride 2048, buf stride 1024
  __hip_bfloat16* VsB = KsB + 8192;
  float* Olds = (float*)smem;                           // [3][16*68] post-loop

  // ---- fused fsc: reduce ssp partials for this bh (rows 0..31 q, 32..63 k) ----
  {
    int row = tid >> 2, part = tid & 3;
    int qk = row >> 5, r32 = row & 31;
    const float* pp = ssp + (size_t)((qk * 2 + b) * 128 + h * 32 + r32) * 64 + part * 16;
    float s = 0.f;
#pragma unroll
    for (int k = 0; k < 16; ++k) s += pp[k];
    s += __shfl_xor(s, 1);
    s += __shfl_xor(s, 2);
    if (part == 0) redl[row] = s;
  }
  __syncthreads();
  if (tid < 32) {
    float vq = 1.f / fmaxf(sqrtf(redl[tid]), 0.1f);
    float vk = 1.f / fmaxf(sqrtf(redl[tid + 32]), 0.1f);
    fscl[tid] = vq * vk * QSCALE_LOG2E;
  }
  __syncthreads();

  const __hip_bfloat16* kg = Kt + (size_t)bh * NSP * DIMH;
  const __hip_bfloat16* vg = Vb + (size_t)bh * DIMH * NSP;

  // Q fragment: fp32 load, scale by fscl, pack to bf16 (single rounding)
  const float* qpf = Qf + ((size_t)bh * NSP + i0 + l31) * DIMH;
  s16x8 qb0, qb1;
  {
    f32x4 a0 = *(const f32x4*)(qpf + hi * 8);
    f32x4 a1 = *(const f32x4*)(qpf + hi * 8 + 4);
    f32x4 a2 = *(const f32x4*)(qpf + 16 + hi * 8);
    f32x4 a3 = *(const f32x4*)(qpf + 16 + hi * 8 + 4);
    f32x4 f0 = *(const f32x4*)(fscl + hi * 8);
    f32x4 f1 = *(const f32x4*)(fscl + hi * 8 + 4);
    f32x4 f2 = *(const f32x4*)(fscl + 16 + hi * 8);
    f32x4 f3 = *(const f32x4*)(fscl + 16 + hi * 8 + 4);
    union { unsigned u[4]; s16x8 v; } p0, p1;
    p0.u[0] = cvtpk_bf16(a0[0] * f0[0], a0[1] * f0[1]);
    p0.u[1] = cvtpk_bf16(a0[2] * f0[2], a0[3] * f0[3]);
    p0.u[2] = cvtpk_bf16(a1[0] * f1[0], a1[1] * f1[1]);
    p0.u[3] = cvtpk_bf16(a1[2] * f1[2], a1[3] * f1[3]);
    p1.u[0] = cvtpk_bf16(a2[0] * f2[0], a2[1] * f2[1]);
    p1.u[1] = cvtpk_bf16(a2[2] * f2[2], a2[3] * f2[3]);
    p1.u[2] = cvtpk_bf16(a3[0] * f3[0], a3[1] * f3[1]);
    p1.u[3] = cvtpk_bf16(a3[2] * f3[2], a3[3] * f3[3]);
    qb0 = p0.v; qb1 = p1.v;
  }

  // staging bases: unit u (0..63 per glds16) -> row u>>2, stored slot u&3,
  // source chunk (u&3) ^ ((row + row>>2)&3). Rows+16 have the SAME phase
  // ((row+16)+((row+16)>>2) = row+row>>2+20 ≡ same mod 4), so the +16-row
  // glds16 reuses the same ch.
  int rw = lane >> 2;                      // 0..15
  int ch = (lane & 3) ^ ((rw + (rw >> 2)) & 3);
  const __hip_bfloat16* ksA = kg + (size_t)rw * DIMH + (ch << 3);
  const __hip_bfloat16* ksB2 = ksA + 16 * DIMH;
  const __hip_bfloat16* vsA = vg + (size_t)rw * NSP + (ch << 3);
  const __hip_bfloat16* vsB2 = vsA + 16 * NSP;
  __hip_bfloat16* kd0 = KsB + wave * 2048;
  __hip_bfloat16* vd0 = VsB + wave * 2048;

  f32x16 O = {};
  float ls0 = 0.f, ls1 = 0.f;

#define STAGE(j0, buf)                                                         \
  {                                                                            \
    glds16(ksA  + (size_t)(j0) * DIMH, kd0 + (buf) * 1024);                    \
    glds16(ksB2 + (size_t)(j0) * DIMH, kd0 + (buf) * 1024 + 512);              \
    glds16(vsA  + (j0), vd0 + (buf) * 1024);                                   \
    glds16(vsB2 + (j0), vd0 + (buf) * 1024 + 512);                             \
  }

  STAGE(jbase, 0);
#pragma unroll 1
  for (int tt = 0; tt < 16; ++tt) {
    int t0 = tt * 2;
    // even step (buf 0)
    STAGE(jbase + (t0 + 1) * 32, 1);
    asm volatile("s_waitcnt vmcnt(4)" ::: "memory");
    attn_sub3(kd0, vd0, l31, hi, qb0, qb1, O, ls0);
    // odd step (buf 1)
    if (tt < 15) {
      STAGE(jbase + (t0 + 2) * 32, 0);
      asm volatile("s_waitcnt vmcnt(4)" ::: "memory");
    } else {
      asm volatile("s_waitcnt vmcnt(0)" ::: "memory");
    }
    attn_sub3(kd0 + 1024, vd0 + 1024, l31, hi, qb0, qb1, O, ls1);
  }
#undef STAGE

  // ---- merge 4 j-quarters (Olds aliases the staging; barrier-separated) ----
  float lsum = ls0 + ls1;
  float lw = lsum + __shfl_xor(lsum, 32);   // full row sum for q-row i = l31 (this jq)
  Llds[wave][lane] = lw;
  __syncthreads();                          // all staging reads complete
  if (wave) {
    float* od = Olds + (size_t)(wave - 1) * 1088;
#pragma unroll
    for (int r = 0; r < 16; ++r) od[r * 68 + lane] = O[r];
  }
  __syncthreads();
  if (wave == 0) {
    float ltot = lw + Llds[1][lane] + Llds[2][lane] + Llds[3][lane];
    if (hi == 0) Llds[0][l31] = ltot;       // reindex by q-row (same-wave DS order)
    float* o0 = Olds;
    float* o1 = o0 + 1088;
    float* o2 = o1 + 1088;
#pragma unroll
    for (int r = 0; r < 16; ++r) {
      int i = (r & 3) + 8 * (r >> 2) + 4 * hi;
      float li = Llds[0][i];
      float sum = O[r] + o0[r * 68 + lane] + o1[r * 68 + lane] + o2[r * 68 + lane];
      o0[r * 68 + lane] = sum / li;
    }
  }
  __syncthreads();
  // store: bf16 n-major. thread -> (row i, 4-channel group cp)
  {
    int i  = (tid >> 3) & 31;       // q-row
    int cp = tid & 7;               // 4 channels each
    int r  = (i & 3) | ((i >> 3) << 2);
    int h2 = (i >> 2) & 1;
    const float* o0 = Olds + r * 68 + h2 * 32 + cp * 4;
    uint2 pv;
    pv.x = cvtpk_bf16(o0[0], o0[1]);
    pv.y = cvtpk_bf16(o0[2], o0[3]);
    __hip_bfloat16* dst = Otb + ((size_t)(b * NSP + i0 + i)) * HID + h * 32 + cp * 4;
    *(uint2*)dst = pv;
  }
}

// ---------------- output projection on MFMA: out[o][n] = sum_c w[o][c]*Ot[n][c] + bias ----------------
__global__ __launch_bounds__(256, 4) void k_projm(const __hip_bfloat16* __restrict__ Otb,
                                                  const float* __restrict__ w,
                                                  const float* __restrict__ bias,
                                                  float* __restrict__ out) {
  int xcd = blockIdx.x & 7;
  int ot  = (blockIdx.x >> 3) & 3;
  int yy  = blockIdx.x >> 5;           // 0..7
  int tile = xcd * 8 + yy;             // 0..63, XCD-local Ot slice
  int n0 = tile * 128;
  int lane = threadIdx.x & 63, wave = threadIdx.x >> 6;
  int l31 = lane & 31, hi = lane >> 5;
  int orow = ot * 32 + l31;

  s16x8 wf[8];
  const float* wr = w + orow * HID + hi * 8;
#pragma unroll
  for (int k = 0; k < 8; ++k) {
    f32x4 a = *(const f32x4*)(wr + k * 16);
    f32x4 b2 = *(const f32x4*)(wr + k * 16 + 4);
    union { unsigned u[4]; s16x8 v; } p;
    p.u[0] = cvtpk_bf16(a[0], a[1]);
    p.u[1] = cvtpk_bf16(a[2], a[3]);
    p.u[2] = cvtpk_bf16(b2[0], b2[1]);
    p.u[3] = cvtpk_bf16(b2[2], b2[3]);
    wf[k] = p.v;
  }

  int nw = n0 + wave * 32;
  int b = nw >> 12, np = nw & 4095;
  const __hip_bfloat16* src = Otb + ((size_t)(b * NSP + np)) * HID;
  f32x16 acc = {};
#pragma unroll
  for (int k = 0; k < 8; ++k) {
    s16x8 bfr = *(const s16x8*)(src + (size_t)l31 * HID + k * 16 + hi * 8);
    acc = __builtin_amdgcn_mfma_f32_32x32x16_bf16(wf[k], bfr, acc, 0, 0, 0);
  }

  float* outb = out + (size_t)b * DIM * NSP + np + l31;
#pragma unroll
  for (int r2 = 0; r2 < 16; ++r2) {
    int o = ot * 32 + (r2 & 3) + 8 * (r2 >> 2) + 4 * hi;
    outb[(size_t)o * NSP] = acc[r2] + bias[o];
  }
}

extern "C" void kernel_launch(void* const* d_in, const int* in_sizes, int n_in,
                              void* d_out, int out_size, void* d_ws, size_t ws_size,
                              hipStream_t stream) {
  const float* x     = (const float*)d_in[0];
  const float* y     = (const float*)d_in[1];
  const float* w_qkv = (const float*)d_in[2];
  const float* w_out = (const float*)d_in[3];
  const float* b_out = (const float*)d_in[4];
  float* out = (float*)d_out;

  char* ws = (char*)d_ws;
  __hip_bfloat16* xt  = (__hip_bfloat16*)(ws);              // 2 MB
  __hip_bfloat16* yt  = (__hip_bfloat16*)(ws + (2  << 20)); // 2 MB
  float* Qf           = (float*)(ws + (4  << 20));          // 4 MB (fp32, unnormalized)
  __hip_bfloat16* Kr  = (__hip_bfloat16*)(ws + (8  << 20)); // 2 MB (bf16, unnormalized)
  __hip_bfloat16* Vb  = (__hip_bfloat16*)(ws + (10 << 20)); // 2 MB
  __hip_bfloat16* Otb = (__hip_bfloat16*)(ws + (12 << 20)); // 2 MB (bf16, n-major)
  float* ssp          = (float*)(ws + (16 << 20));          // 128 KB partial sums

  k_cvt   <<<256,  256, 0, stream>>>(x, y, xt, yt);
  k_qkvm  <<<384,  256, 0, stream>>>(xt, yt, w_qkv, ssp, Qf, Kr, Vb);
  k_attn  <<<1024, 256, 0, stream>>>(Qf, Kr, Vb, ssp, Otb);
  k_projm <<<256,  256, 0, stream>>>(Otb, w_out, b_out, out);
}

// Round 19
// 57.745 us; speedup vs baseline: 1.0869x; 1.0869x over previous
//
#include <hip/hip_runtime.h>
#include <hip/hip_bf16.h>

#define HEADS 4
#define DIMH  32
#define HID   128
#define DIM   128
#define NSP   4096
// 10 * log2(e); folded into the per-channel factor f = scq*sck*QSCALE_LOG2E.
#define QSCALE_LOG2E 14.426950408889634f

typedef __attribute__((ext_vector_type(4)))  float f32x4;
typedef __attribute__((ext_vector_type(16))) float f32x16;
typedef __attribute__((ext_vector_type(8)))  short s16x8;

__device__ __forceinline__ unsigned cvtpk_bf16(float a, float b) {
  unsigned d;
  asm("v_cvt_pk_bf16_f32 %0, %1, %2" : "=v"(d) : "v"(a), "v"(b));
  return d;
}

// ---------------- convert+transpose x,y fp32 [b][c][n] -> bf16 [b*n][c] ----------------
__global__ __launch_bounds__(256) void k_cvt(const float* __restrict__ x,
                                             const float* __restrict__ y,
                                             __hip_bfloat16* __restrict__ xt,
                                             __hip_bfloat16* __restrict__ yt) {
  int bid = blockIdx.x;          // 2 tensor * 2 b * 64 ntiles
  int t = bid >> 7, rem = bid & 127;
  int b = rem >> 6, nt = rem & 63;
  int n0 = nt * 64;
  const float* src = (t ? y : x) + (size_t)b * DIM * NSP;
  __hip_bfloat16* dst = (t ? yt : xt) + (size_t)b * NSP * DIM;

  __shared__ alignas(16) __hip_bfloat16 tile[64 * 136];
  int n = threadIdx.x & 63, c0 = threadIdx.x >> 6;   // c0 0..3
  const float* sp = src + n0 + n;
#pragma unroll
  for (int cc = 0; cc < 32; ++cc) {
    int c = cc * 4 + c0;
    tile[n * 136 + c] = __float2bfloat16(sp[(size_t)c * NSP]);
  }
  __syncthreads();
  int rrow = threadIdx.x >> 2, cb = (threadIdx.x & 3) * 32;
  __hip_bfloat16* op = dst + (size_t)(n0 + rrow) * DIM + cb;
  const __hip_bfloat16* ip = tile + rrow * 136 + cb;
#pragma unroll
  for (int k = 0; k < 4; ++k)
    *(s16x8*)(op + k * 8) = *(const s16x8*)(ip + k * 8);
}

// ---------------- QKV GEMM on MFMA ----------------
// orows 0..127 = Q (fp32 out), 128..255 = K (bf16), 256..383 = V (bf16).
// Sum-of-squares: deterministic per-wave partials into ssp[512][64] (no atomics).
__global__ __launch_bounds__(256, 4) void k_qkvm(const __hip_bfloat16* __restrict__ xt,
                                                 const __hip_bfloat16* __restrict__ yt,
                                                 const float* __restrict__ w,
                                                 float* __restrict__ ssp,
                                                 float* __restrict__ Qf,
                                                 __hip_bfloat16* __restrict__ Kr,
                                                 __hip_bfloat16* __restrict__ Vb) {
  int xcd = blockIdx.x & 7;
  int r = blockIdx.x >> 3;        // 0..47
  int ot = r >> 2;                // 0..11
  int nts = r & 3;
  int tile = xcd * 4 + nts;       // n-tile 0..31
  int n0 = tile * 256;
  int lane = threadIdx.x & 63, wave = threadIdx.x >> 6;
  int l31 = lane & 31, hi = lane >> 5;
  int orow = ot * 32 + l31;

  s16x8 wf[8];
  const float* wr = w + orow * DIM + hi * 8;
#pragma unroll
  for (int k = 0; k < 8; ++k) {
    f32x4 a = *(const f32x4*)(wr + k * 16);
    f32x4 b2 = *(const f32x4*)(wr + k * 16 + 4);
    union { unsigned u[4]; s16x8 v; } p;
    p.u[0] = cvtpk_bf16(a[0], a[1]);
    p.u[1] = cvtpk_bf16(a[2], a[3]);
    p.u[2] = cvtpk_bf16(b2[0], b2[1]);
    p.u[3] = cvtpk_bf16(b2[2], b2[3]);
    wf[k] = p.v;
  }

  const __hip_bfloat16* src = (ot < 4 ? xt : yt);
  int nw = n0 + wave * 64;
  f32x16 acc0 = {}, acc1 = {};
#pragma unroll
  for (int k = 0; k < 8; ++k) {
    s16x8 b0 = *(const s16x8*)(src + (size_t)(nw + l31) * DIM + k * 16 + hi * 8);
    s16x8 b1 = *(const s16x8*)(src + (size_t)(nw + 32 + l31) * DIM + k * 16 + hi * 8);
    acc0 = __builtin_amdgcn_mfma_f32_32x32x16_bf16(wf[k], b0, acc0, 0, 0, 0);
    acc1 = __builtin_amdgcn_mfma_f32_32x32x16_bf16(wf[k], b1, acc1, 0, 0, 0);
  }

  int b = nw >> 12;
  if (ot < 8) {
    int h = ot & 3;
    if (ot < 4) {
#pragma unroll
      for (int nt = 0; nt < 2; ++nt) {
        int np = (nw + nt * 32 + l31) & 4095;
        float* base = Qf + ((size_t)((b * HEADS + h) * NSP + np)) * DIMH;
        const f32x16& A = nt ? acc1 : acc0;
#pragma unroll
        for (int m = 0; m < 4; ++m) {
          f32x4 v = { A[4 * m], A[4 * m + 1], A[4 * m + 2], A[4 * m + 3] };
          *(f32x4*)(base + 8 * m + 4 * hi) = v;
        }
      }
    } else {
#pragma unroll
      for (int nt = 0; nt < 2; ++nt) {
        int np = (nw + nt * 32 + l31) & 4095;
        __hip_bfloat16* base = Kr + ((size_t)((b * HEADS + h) * NSP + np)) * DIMH;
        const f32x16& A = nt ? acc1 : acc0;
#pragma unroll
        for (int m = 0; m < 4; ++m) {
          uint2 p2;
          p2.x = cvtpk_bf16(A[4 * m], A[4 * m + 1]);
          p2.y = cvtpk_bf16(A[4 * m + 2], A[4 * m + 3]);
          *(uint2*)(base + 8 * m + 4 * hi) = p2;
        }
      }
    }
    float p[16];
#pragma unroll
    for (int r2 = 0; r2 < 16; ++r2) p[r2] = acc0[r2] * acc0[r2] + acc1[r2] * acc1[r2];
#pragma unroll
    for (int r2 = 0; r2 < 16; ++r2) {
#pragma unroll
      for (int m2 = 1; m2 < 32; m2 <<= 1) p[r2] += __shfl_xor(p[r2], m2);
    }
    if (l31 == 0) {
      int t = (ot < 4 ? 0 : 1);
      int widx = (tile & 15) * 4 + wave;              // 0..63
      int rbase = (t * 2 + b) * 128 + h * 32;
#pragma unroll
      for (int r2 = 0; r2 < 16; ++r2) {
        int row = (r2 & 3) + 8 * (r2 >> 2) + 4 * hi;
        ssp[(size_t)(rbase + row) * 64 + widx] = p[r2];
      }
    }
  } else {
    int h = ot - 8;
#pragma unroll
    for (int nt = 0; nt < 2; ++nt) {
      int np = (nw + nt * 32 + l31) & 4095;
      const f32x16& A = nt ? acc1 : acc0;
#pragma unroll
      for (int r2 = 0; r2 < 16; ++r2) {
        int d = (r2 & 3) + 8 * (r2 >> 2) + 4 * hi;
        Vb[((size_t)((b * HEADS + h) * DIMH + d)) * NSP + np] = __float2bfloat16(A[r2]);
      }
    }
  }
}

// ---------------- flash attention: shared LDS staging, phase-swizzled K AND V ----------------
__device__ __forceinline__ void glds16(const __hip_bfloat16* g, __hip_bfloat16* l) {
  __builtin_amdgcn_global_load_lds(
      (const __attribute__((address_space(1))) unsigned int*)(const void*)g,
      (__attribute__((address_space(3))) unsigned int*)(void*)l, 16, 0, 0);
}

// One 32(q-rows) x 32(j) subtile from shared LDS tiles.
// K: 64B rows, phase (row + row>>2)&3 -> only l<->l+16 alias (free 2-way).
// V: 128B rows, phase (row + row>>3)&7 -> lanes l,l+8,l+16,l+24 hit distinct slots.
__device__ __forceinline__ void attn_sub2(const __hip_bfloat16* kbase,
                                          const __hip_bfloat16* vbase,
                                          int s, int l31, int hi,
                                          s16x8 qb0, s16x8 qb1,
                                          f32x16& O, float& lsum) {
  int krx = (l31 + (l31 >> 2)) & 3;
  int vrx = (l31 + (l31 >> 3)) & 7;
  const __hip_bfloat16* krow = kbase + (s * 32 + l31) * DIMH;
  s16x8 kf0 = *(const s16x8*)(krow + (((hi) ^ krx) << 3));
  s16x8 kf1 = *(const s16x8*)(krow + (((2 + hi) ^ krx) << 3));
  f32x16 z = {};
  f32x16 sv = __builtin_amdgcn_mfma_f32_32x32x16_bf16(kf0, qb0, z, 0, 0, 0);
  sv        = __builtin_amdgcn_mfma_f32_32x32x16_bf16(kf1, qb1, sv, 0, 0, 0);
  float p[16];
#pragma unroll
  for (int r = 0; r < 16; ++r) p[r] = __builtin_amdgcn_exp2f(sv[r]);
  float t0 = 0.f, t1 = 0.f;
#pragma unroll
  for (int r = 0; r < 16; r += 2) { t0 += p[r]; t1 += p[r + 1]; }
  lsum += t0 + t1;
  unsigned wA[4], wB[4];
#pragma unroll
  for (int m = 0; m < 4; ++m) {
    wA[m] = cvtpk_bf16(p[4 * m], p[4 * m + 1]);
    wB[m] = cvtpk_bf16(p[4 * m + 2], p[4 * m + 3]);
  }
  const __hip_bfloat16* vrow = vbase + l31 * 64;
#define PV_CHUNK(c2, vfrag)                                                    \
  {                                                                            \
    unsigned a0 = wA[2 * (c2)], a1 = wA[2 * (c2) + 1];                         \
    unsigned b0 = wB[2 * (c2)], b1 = wB[2 * (c2) + 1];                         \
    asm("v_permlane32_swap_b32 %0, %1" : "+v"(a0), "+v"(a1));                  \
    asm("v_permlane32_swap_b32 %0, %1" : "+v"(b0), "+v"(b1));                  \
    union { unsigned u[4]; s16x8 v; } pa;                                      \
    pa.u[0] = a0; pa.u[1] = b0; pa.u[2] = a1; pa.u[3] = b1;                    \
    O = __builtin_amdgcn_mfma_f32_32x32x16_bf16(pa.v, vfrag, O, 0, 0, 0);      \
  }
#pragma unroll
  for (int c2 = 0; c2 < 2; ++c2) {
    int cc = s * 2 + c2;
    s16x8 vf = *(const s16x8*)(vrow + (((cc * 2 + hi) ^ vrx) << 3));
    PV_CHUNK(c2, vf);
  }
#undef PV_CHUNK
}

// 8 waves (2 qsub x 4 jq), 64 q-rows x full j per block; grid 512 (8 bh XCD-local x 64 qt)
// -> 2 blocks/CU: two independent barrier domains overlap each other's vmcnt drains.
// fsc reduction fused in prologue. Output bf16 n-major.
__global__ __launch_bounds__(512, 4) void k_attn(const float* __restrict__ Qf,
                                                 const __hip_bfloat16* __restrict__ Kt,
                                                 const __hip_bfloat16* __restrict__ Vb,
                                                 const float* __restrict__ ssp,
                                                 __hip_bfloat16* __restrict__ Otb) {
  int bh = blockIdx.x & 7, qt = blockIdx.x >> 3;   // 8 bh x 64 qt
  int tid = threadIdx.x, lane = tid & 63, wave = tid >> 6;
  int qsub = wave & 1, jq = wave >> 1;
  int l31 = lane & 31, hi = lane >> 5;
  int i0 = qt * 64 + qsub * 32;
  int jbase = jq * 1024;
  int b = bh >> 2, h = bh & 3;

  __shared__ alignas(16) char smem[65536];   // Ks 32KB + Vs 32KB; Olds aliased post-loop
  __shared__ float Llds[8][64];
  __shared__ float redl[64];
  __shared__ float fscl[32];
  __hip_bfloat16* KsB = (__hip_bfloat16*)smem;            // [4 jq][2 buf][2048]
  __hip_bfloat16* VsB = KsB + 16384;                      // [4 jq][2 buf][2048]
  float* Olds = (float*)smem;                             // [2 qsub][3][16*68] post-loop

  // ---- fused fsc: reduce ssp partials for this bh (rows 0..31 q, 32..63 k) ----
  {
    int row = tid >> 3, part = tid & 7;
    int qk = row >> 5, r32 = row & 31;
    const float* pp = ssp + (size_t)((qk * 2 + b) * 128 + h * 32 + r32) * 64 + part * 8;
    float s = 0.f;
#pragma unroll
    for (int k = 0; k < 8; ++k) s += pp[k];
    s += __shfl_xor(s, 1);
    s += __shfl_xor(s, 2);
    s += __shfl_xor(s, 4);
    if (part == 0) redl[row] = s;
  }
  __syncthreads();
  if (tid < 32) {
    float vq = 1.f / fmaxf(sqrtf(redl[tid]), 0.1f);
    float vk = 1.f / fmaxf(sqrtf(redl[tid + 32]), 0.1f);
    fscl[tid] = vq * vk * QSCALE_LOG2E;
  }
  __syncthreads();

  const __hip_bfloat16* kg = Kt + (size_t)bh * NSP * DIMH;
  const __hip_bfloat16* vg = Vb + (size_t)bh * DIMH * NSP;

  // Q fragment: fp32 load, scale by fscl, pack to bf16 (single rounding)
  const float* qpf = Qf + ((size_t)bh * NSP + i0 + l31) * DIMH;
  s16x8 qb0, qb1;
  {
    f32x4 a0 = *(const f32x4*)(qpf + hi * 8);
    f32x4 a1 = *(const f32x4*)(qpf + hi * 8 + 4);
    f32x4 a2 = *(const f32x4*)(qpf + 16 + hi * 8);
    f32x4 a3 = *(const f32x4*)(qpf + 16 + hi * 8 + 4);
    f32x4 f0 = *(const f32x4*)(fscl + hi * 8);
    f32x4 f1 = *(const f32x4*)(fscl + hi * 8 + 4);
    f32x4 f2 = *(const f32x4*)(fscl + 16 + hi * 8);
    f32x4 f3 = *(const f32x4*)(fscl + 16 + hi * 8 + 4);
    union { unsigned u[4]; s16x8 v; } p0, p1;
    p0.u[0] = cvtpk_bf16(a0[0] * f0[0], a0[1] * f0[1]);
    p0.u[1] = cvtpk_bf16(a0[2] * f0[2], a0[3] * f0[3]);
    p0.u[2] = cvtpk_bf16(a1[0] * f1[0], a1[1] * f1[1]);
    p0.u[3] = cvtpk_bf16(a1[2] * f1[2], a1[3] * f1[3]);
    p1.u[0] = cvtpk_bf16(a2[0] * f2[0], a2[1] * f2[1]);
    p1.u[1] = cvtpk_bf16(a2[2] * f2[2], a2[3] * f2[3]);
    p1.u[2] = cvtpk_bf16(a3[0] * f3[0], a3[1] * f3[1]);
    p1.u[3] = cvtpk_bf16(a3[2] * f3[2], a3[3] * f3[3]);
    qb0 = p0.v; qb1 = p1.v;
  }

  // stager: 128 lanes (2 qsub x 64); each lane stages units ku and ku+128.
  // K unit u: row u>>2 (stride 64B), slot u&3, source chunk (u&3)^((row+row>>2)&3).
  //   Unit u+128 -> row+32: phase identical mod 4 -> same chunk, source +1024 elems.
  // V unit u: row u>>3 (stride 128B), slot u&7, source chunk (u&7)^((row+row>>3)&7).
  //   Unit u+128 -> row+16: phase differs -> separate base pointer.
  int ku = qsub * 64 + lane;                 // 0..127
  int krow = ku >> 2;
  int kch = (ku & 3) ^ ((krow + (krow >> 2)) & 3);
  const __hip_bfloat16* ksrc0 = kg + (size_t)krow * DIMH + (kch << 3);
  int vdA = ku >> 3;
  int vchA = (ku & 7) ^ ((vdA + (vdA >> 3)) & 7);
  const __hip_bfloat16* vsrcA = vg + (size_t)vdA * NSP + (vchA << 3);
  int vdB = vdA + 16;
  int vchB = (ku & 7) ^ ((vdB + (vdB >> 3)) & 7);
  const __hip_bfloat16* vsrcB = vg + (size_t)vdB * NSP + (vchB << 3);

  f32x16 O = {};
  float ls0 = 0.f, ls1 = 0.f;

#define STAGE(j0, buf)                                                         \
  {                                                                            \
    __hip_bfloat16* kd = KsB + (jq * 2 + (buf)) * 2048;                        \
    __hip_bfloat16* vd = VsB + (jq * 2 + (buf)) * 2048;                        \
    glds16(ksrc0 + (size_t)(j0) * DIMH,      kd + qsub * 512);                 \
    glds16(ksrc0 + (size_t)(j0 + 32) * DIMH, kd + 1024 + qsub * 512);          \
    glds16(vsrcA + (j0), vd + qsub * 512);                                     \
    glds16(vsrcB + (j0), vd + 1024 + qsub * 512);                              \
  }

  STAGE(jbase, 0);
  asm volatile("s_waitcnt vmcnt(0)" ::: "memory");
  __syncthreads();

#pragma unroll 1
  for (int t = 0; t < 16; ++t) {
    int buf = t & 1;
    if (t < 15) STAGE(jbase + (t + 1) * 64, buf ^ 1);
    const __hip_bfloat16* kbase = KsB + (jq * 2 + buf) * 2048;
    const __hip_bfloat16* vbase = VsB + (jq * 2 + buf) * 2048;
    attn_sub2(kbase, vbase, 0, l31, hi, qb0, qb1, O, ls0);
    attn_sub2(kbase, vbase, 1, l31, hi, qb0, qb1, O, ls1);
    if (t < 15) {
      asm volatile("s_waitcnt vmcnt(0)" ::: "memory");
      __syncthreads();
    }
  }
#undef STAGE

  // ---- merge 4 j-quarters (Olds aliases the staging; barrier-separated) ----
  float lsum = ls0 + ls1;
  float lw = lsum + __shfl_xor(lsum, 32);   // full row sum for q-row i = l31 (this jq)
  Llds[wave][lane] = lw;
  __syncthreads();                          // all staging reads complete
  if (jq) {
    float* od = Olds + (size_t)(qsub * 3 + (jq - 1)) * 1088;
#pragma unroll
    for (int r = 0; r < 16; ++r) od[r * 68 + lane] = O[r];
  }
  __syncthreads();
  if (jq == 0) {
    float ltot = lw + Llds[wave + 2][lane] + Llds[wave + 4][lane] + Llds[wave + 6][lane];
    if (hi == 0) Llds[wave][l31] = ltot;    // reindex by q-row (same-wave DS order)
    float* o0 = Olds + (size_t)(qsub * 3) * 1088;
    float* o1 = o0 + 1088;
    float* o2 = o1 + 1088;
#pragma unroll
    for (int r = 0; r < 16; ++r) {
      int i = (r & 3) + 8 * (r >> 2) + 4 * hi;
      float li = Llds[wave][i];
      float sum = O[r] + o0[r * 68 + lane] + o1[r * 68 + lane] + o2[r * 68 + lane];
      o0[r * 68 + lane] = sum / li;
    }
  }
  __syncthreads();
  // store: bf16 n-major. thread -> (qsub q2, row i, 4-channel group cp)
  {
    int q2 = tid >> 8;              // 0..1
    int i  = (tid >> 3) & 31;       // q-row within qsub tile
    int cp = tid & 7;               // 4 channels each
    int r  = (i & 3) | ((i >> 3) << 2);
    int h2 = (i >> 2) & 1;
    const float* o0 = Olds + (size_t)(q2 * 3) * 1088 + r * 68 + h2 * 32 + cp * 4;
    uint2 pv;
    pv.x = cvtpk_bf16(o0[0], o0[1]);
    pv.y = cvtpk_bf16(o0[2], o0[3]);
    __hip_bfloat16* dst = Otb + ((size_t)(b * NSP + qt * 64 + q2 * 32 + i)) * HID + h * 32 + cp * 4;
    *(uint2*)dst = pv;
  }
}

// ---------------- output projection on MFMA: out[o][n] = sum_c w[o][c]*Ot[n][c] + bias ----------------
__global__ __launch_bounds__(256, 4) void k_projm(const __hip_bfloat16* __restrict__ Otb,
                                                  const float* __restrict__ w,
                                                  const float* __restrict__ bias,
                                                  float* __restrict__ out) {
  int xcd = blockIdx.x & 7;
  int ot  = (blockIdx.x >> 3) & 3;
  int yy  = blockIdx.x >> 5;           // 0..7
  int tile = xcd * 8 + yy;             // 0..63, XCD-local Ot slice
  int n0 = tile * 128;
  int lane = threadIdx.x & 63, wave = threadIdx.x >> 6;
  int l31 = lane & 31, hi = lane >> 5;
  int orow = ot * 32 + l31;

  s16x8 wf[8];
  const float* wr = w + orow * HID + hi * 8;
#pragma unroll
  for (int k = 0; k < 8; ++k) {
    f32x4 a = *(const f32x4*)(wr + k * 16);
    f32x4 b2 = *(const f32x4*)(wr + k * 16 + 4);
    union { unsigned u[4]; s16x8 v; } p;
    p.u[0] = cvtpk_bf16(a[0], a[1]);
    p.u[1] = cvtpk_bf16(a[2], a[3]);
    p.u[2] = cvtpk_bf16(b2[0], b2[1]);
    p.u[3] = cvtpk_bf16(b2[2], b2[3]);
    wf[k] = p.v;
  }

  int nw = n0 + wave * 32;
  int b = nw >> 12, np = nw & 4095;
  const __hip_bfloat16* src = Otb + ((size_t)(b * NSP + np)) * HID;
  f32x16 acc = {};
#pragma unroll
  for (int k = 0; k < 8; ++k) {
    s16x8 bfr = *(const s16x8*)(src + (size_t)l31 * HID + k * 16 + hi * 8);
    acc = __builtin_amdgcn_mfma_f32_32x32x16_bf16(wf[k], bfr, acc, 0, 0, 0);
  }

  float* outb = out + (size_t)b * DIM * NSP + np + l31;
#pragma unroll
  for (int r2 = 0; r2 < 16; ++r2) {
    int o = ot * 32 + (r2 & 3) + 8 * (r2 >> 2) + 4 * hi;
    outb[(size_t)o * NSP] = acc[r2] + bias[o];
  }
}

extern "C" void kernel_launch(void* const* d_in, const int* in_sizes, int n_in,
                              void* d_out, int out_size, void* d_ws, size_t ws_size,
                              hipStream_t stream) {
  const float* x     = (const float*)d_in[0];
  const float* y     = (const float*)d_in[1];
  const float* w_qkv = (const float*)d_in[2];
  const float* w_out = (const float*)d_in[3];
  const float* b_out = (const float*)d_in[4];
  float* out = (float*)d_out;

  char* ws = (char*)d_ws;
  __hip_bfloat16* xt  = (__hip_bfloat16*)(ws);              // 2 MB
  __hip_bfloat16* yt  = (__hip_bfloat16*)(ws + (2  << 20)); // 2 MB
  float* Qf           = (float*)(ws + (4  << 20));          // 4 MB (fp32, unnormalized)
  __hip_bfloat16* Kr  = (__hip_bfloat16*)(ws + (8  << 20)); // 2 MB (bf16, unnormalized)
  __hip_bfloat16* Vb  = (__hip_bfloat16*)(ws + (10 << 20)); // 2 MB
  __hip_bfloat16* Otb = (__hip_bfloat16*)(ws + (12 << 20)); // 2 MB (bf16, n-major)
  float* ssp          = (float*)(ws + (16 << 20));          // 128 KB partial sums

  k_cvt   <<<256, 256, 0, stream>>>(x, y, xt, yt);
  k_qkvm  <<<384, 256, 0, stream>>>(xt, yt, w_qkv, ssp, Qf, Kr, Vb);
  k_attn  <<<512, 512, 0, stream>>>(Qf, Kr, Vb, ssp, Otb);
  k_projm <<<256, 256, 0, stream>>>(Otb, w_out, b_out, out);
}

// Round 20
// 57.693 us; speedup vs baseline: 1.0879x; 1.0009x over previous
//
#include <hip/hip_runtime.h>
#include <hip/hip_bf16.h>

#define HEADS 4
#define DIMH  32
#define HID   128
#define DIM   128
#define NSP   4096
// 10 * log2(e); folded into the per-channel factor f = scq*sck*QSCALE_LOG2E.
#define QSCALE_LOG2E 14.426950408889634f

typedef __attribute__((ext_vector_type(4)))  float f32x4;
typedef __attribute__((ext_vector_type(16))) float f32x16;
typedef __attribute__((ext_vector_type(8)))  short s16x8;

__device__ __forceinline__ unsigned cvtpk_bf16(float a, float b) {
  unsigned d;
  asm("v_cvt_pk_bf16_f32 %0, %1, %2" : "=v"(d) : "v"(a), "v"(b));
  return d;
}

// ---------------- convert+transpose x,y fp32 [b][c][n] -> bf16 [b*n][c] ----------------
__global__ __launch_bounds__(256) void k_cvt(const float* __restrict__ x,
                                             const float* __restrict__ y,
                                             __hip_bfloat16* __restrict__ xt,
                                             __hip_bfloat16* __restrict__ yt) {
  int bid = blockIdx.x;          // 2 tensor * 2 b * 64 ntiles
  int t = bid >> 7, rem = bid & 127;
  int b = rem >> 6, nt = rem & 63;
  int n0 = nt * 64;
  const float* src = (t ? y : x) + (size_t)b * DIM * NSP;
  __hip_bfloat16* dst = (t ? yt : xt) + (size_t)b * NSP * DIM;

  __shared__ alignas(16) __hip_bfloat16 tile[64 * 136];
  int n = threadIdx.x & 63, c0 = threadIdx.x >> 6;   // c0 0..3
  const float* sp = src + n0 + n;
#pragma unroll
  for (int cc = 0; cc < 32; ++cc) {
    int c = cc * 4 + c0;
    tile[n * 136 + c] = __float2bfloat16(sp[(size_t)c * NSP]);
  }
  __syncthreads();
  int rrow = threadIdx.x >> 2, cb = (threadIdx.x & 3) * 32;
  __hip_bfloat16* op = dst + (size_t)(n0 + rrow) * DIM + cb;
  const __hip_bfloat16* ip = tile + rrow * 136 + cb;
#pragma unroll
  for (int k = 0; k < 4; ++k)
    *(s16x8*)(op + k * 8) = *(const s16x8*)(ip + k * 8);
}

// ---------------- QKV GEMM on MFMA ----------------
// orows 0..127 = Q (fp32 out), 128..255 = K (bf16), 256..383 = V (bf16).
// Sum-of-squares: deterministic per-wave partials into ssp[512][64] (no atomics).
__global__ __launch_bounds__(256, 4) void k_qkvm(const __hip_bfloat16* __restrict__ xt,
                                                 const __hip_bfloat16* __restrict__ yt,
                                                 const float* __restrict__ w,
                                                 float* __restrict__ ssp,
                                                 float* __restrict__ Qf,
                                                 __hip_bfloat16* __restrict__ Kr,
                                                 __hip_bfloat16* __restrict__ Vb) {
  int xcd = blockIdx.x & 7;
  int r = blockIdx.x >> 3;        // 0..47
  int ot = r >> 2;                // 0..11
  int nts = r & 3;
  int tile = xcd * 4 + nts;       // n-tile 0..31
  int n0 = tile * 256;
  int lane = threadIdx.x & 63, wave = threadIdx.x >> 6;
  int l31 = lane & 31, hi = lane >> 5;
  int orow = ot * 32 + l31;

  s16x8 wf[8];
  const float* wr = w + orow * DIM + hi * 8;
#pragma unroll
  for (int k = 0; k < 8; ++k) {
    f32x4 a = *(const f32x4*)(wr + k * 16);
    f32x4 b2 = *(const f32x4*)(wr + k * 16 + 4);
    union { unsigned u[4]; s16x8 v; } p;
    p.u[0] = cvtpk_bf16(a[0], a[1]);
    p.u[1] = cvtpk_bf16(a[2], a[3]);
    p.u[2] = cvtpk_bf16(b2[0], b2[1]);
    p.u[3] = cvtpk_bf16(b2[2], b2[3]);
    wf[k] = p.v;
  }

  const __hip_bfloat16* src = (ot < 4 ? xt : yt);
  int nw = n0 + wave * 64;
  f32x16 acc0 = {}, acc1 = {};
#pragma unroll
  for (int k = 0; k < 8; ++k) {
    s16x8 b0 = *(const s16x8*)(src + (size_t)(nw + l31) * DIM + k * 16 + hi * 8);
    s16x8 b1 = *(const s16x8*)(src + (size_t)(nw + 32 + l31) * DIM + k * 16 + hi * 8);
    acc0 = __builtin_amdgcn_mfma_f32_32x32x16_bf16(wf[k], b0, acc0, 0, 0, 0);
    acc1 = __builtin_amdgcn_mfma_f32_32x32x16_bf16(wf[k], b1, acc1, 0, 0, 0);
  }

  int b = nw >> 12;
  if (ot < 8) {
    int h = ot & 3;
    if (ot < 4) {
#pragma unroll
      for (int nt = 0; nt < 2; ++nt) {
        int np = (nw + nt * 32 + l31) & 4095;
        float* base = Qf + ((size_t)((b * HEADS + h) * NSP + np)) * DIMH;
        const f32x16& A = nt ? acc1 : acc0;
#pragma unroll
        for (int m = 0; m < 4; ++m) {
          f32x4 v = { A[4 * m], A[4 * m + 1], A[4 * m + 2], A[4 * m + 3] };
          *(f32x4*)(base + 8 * m + 4 * hi) = v;
        }
      }
    } else {
#pragma unroll
      for (int nt = 0; nt < 2; ++nt) {
        int np = (nw + nt * 32 + l31) & 4095;
        __hip_bfloat16* base = Kr + ((size_t)((b * HEADS + h) * NSP + np)) * DIMH;
        const f32x16& A = nt ? acc1 : acc0;
#pragma unroll
        for (int m = 0; m < 4; ++m) {
          uint2 p2;
          p2.x = cvtpk_bf16(A[4 * m], A[4 * m + 1]);
          p2.y = cvtpk_bf16(A[4 * m + 2], A[4 * m + 3]);
          *(uint2*)(base + 8 * m + 4 * hi) = p2;
        }
      }
    }
    float p[16];
#pragma unroll
    for (int r2 = 0; r2 < 16; ++r2) p[r2] = acc0[r2] * acc0[r2] + acc1[r2] * acc1[r2];
#pragma unroll
    for (int r2 = 0; r2 < 16; ++r2) {
#pragma unroll
      for (int m2 = 1; m2 < 32; m2 <<= 1) p[r2] += __shfl_xor(p[r2], m2);
    }
    if (l31 == 0) {
      int t = (ot < 4 ? 0 : 1);
      int widx = (tile & 15) * 4 + wave;              // 0..63
      int rbase = (t * 2 + b) * 128 + h * 32;
#pragma unroll
      for (int r2 = 0; r2 < 16; ++r2) {
        int row = (r2 & 3) + 8 * (r2 >> 2) + 4 * hi;
        ssp[(size_t)(rbase + row) * 64 + widx] = p[r2];
      }
    }
  } else {
    int h = ot - 8;
#pragma unroll
    for (int nt = 0; nt < 2; ++nt) {
      int np = (nw + nt * 32 + l31) & 4095;
      const f32x16& A = nt ? acc1 : acc0;
#pragma unroll
      for (int r2 = 0; r2 < 16; ++r2) {
        int d = (r2 & 3) + 8 * (r2 >> 2) + 4 * hi;
        Vb[((size_t)((b * HEADS + h) * DIMH + d)) * NSP + np] = __float2bfloat16(A[r2]);
      }
    }
  }
}

// ---------------- flash attention: 3-buffer counted-vmcnt pipeline, shared staging ----------------
__device__ __forceinline__ void glds16(const __hip_bfloat16* g, __hip_bfloat16* l) {
  __builtin_amdgcn_global_load_lds(
      (const __attribute__((address_space(1))) unsigned int*)(const void*)g,
      (__attribute__((address_space(3))) unsigned int*)(void*)l, 16, 0, 0);
}

// One 32(q-rows) x 32(j) subtile from shared LDS tiles.
// K: 64B rows, phase (row + row>>2)&3. V: 128B rows, phase (row + row>>3)&7.
// Both hit the b128 bank floor (no excess conflicts; verified R18: 33K).
__device__ __forceinline__ void attn_sub2(const __hip_bfloat16* kbase,
                                          const __hip_bfloat16* vbase,
                                          int s, int l31, int hi,
                                          s16x8 qb0, s16x8 qb1,
                                          f32x16& O, float& lsum) {
  int krx = (l31 + (l31 >> 2)) & 3;
  int vrx = (l31 + (l31 >> 3)) & 7;
  const __hip_bfloat16* krow = kbase + (s * 32 + l31) * DIMH;
  s16x8 kf0 = *(const s16x8*)(krow + (((hi) ^ krx) << 3));
  s16x8 kf1 = *(const s16x8*)(krow + (((2 + hi) ^ krx) << 3));
  f32x16 z = {};
  f32x16 sv = __builtin_amdgcn_mfma_f32_32x32x16_bf16(kf0, qb0, z, 0, 0, 0);
  sv        = __builtin_amdgcn_mfma_f32_32x32x16_bf16(kf1, qb1, sv, 0, 0, 0);
  float p[16];
#pragma unroll
  for (int r = 0; r < 16; ++r) p[r] = __builtin_amdgcn_exp2f(sv[r]);
  float t0 = 0.f, t1 = 0.f;
#pragma unroll
  for (int r = 0; r < 16; r += 2) { t0 += p[r]; t1 += p[r + 1]; }
  lsum += t0 + t1;
  unsigned wA[4], wB[4];
#pragma unroll
  for (int m = 0; m < 4; ++m) {
    wA[m] = cvtpk_bf16(p[4 * m], p[4 * m + 1]);
    wB[m] = cvtpk_bf16(p[4 * m + 2], p[4 * m + 3]);
  }
  const __hip_bfloat16* vrow = vbase + l31 * 64;
#define PV_CHUNK(c2, vfrag)                                                    \
  {                                                                            \
    unsigned a0 = wA[2 * (c2)], a1 = wA[2 * (c2) + 1];                         \
    unsigned b0 = wB[2 * (c2)], b1 = wB[2 * (c2) + 1];                         \
    asm("v_permlane32_swap_b32 %0, %1" : "+v"(a0), "+v"(a1));                  \
    asm("v_permlane32_swap_b32 %0, %1" : "+v"(b0), "+v"(b1));                  \
    union { unsigned u[4]; s16x8 v; } pa;                                      \
    pa.u[0] = a0; pa.u[1] = b0; pa.u[2] = a1; pa.u[3] = b1;                    \
    O = __builtin_amdgcn_mfma_f32_32x32x16_bf16(pa.v, vfrag, O, 0, 0, 0);      \
  }
#pragma unroll
  for (int c2 = 0; c2 < 2; ++c2) {
    int cc = s * 2 + c2;
    s16x8 vf = *(const s16x8*)(vrow + (((cc * 2 + hi) ^ vrx) << 3));
    PV_CHUNK(c2, vf);
  }
#undef PV_CHUNK
}

// 16 waves (4 qsub x 4 jq), 128 q-rows x full j; grid 256 (8 bh XCD-local x 32 qt).
// TRIPLE-buffered shared staging with counted vmcnt(2) + raw s_barrier:
// loads stay in flight across barriers (T4); no drain-to-0 in the main loop.
// Race-freedom: buffer (t+2)%3 written at iter t was last read at iter t-1 (barrier-
// separated); vmcnt(2) before each barrier proves STAGE(t+1) landed (2 glds16/STAGE).
__global__ __launch_bounds__(1024, 4) void k_attn(const float* __restrict__ Qf,
                                                  const __hip_bfloat16* __restrict__ Kt,
                                                  const __hip_bfloat16* __restrict__ Vb,
                                                  const float* __restrict__ ssp,
                                                  __hip_bfloat16* __restrict__ Otb) {
  int bh = blockIdx.x & 7, qt = blockIdx.x >> 3;   // 8 bh x 32 qt
  int tid = threadIdx.x, lane = tid & 63, wave = tid >> 6;
  int qsub = wave & 3, jq = wave >> 2;
  int l31 = lane & 31, hi = lane >> 5;
  int i0 = qt * 128 + qsub * 32;
  int jbase = jq * 1024;
  int b = bh >> 2, h = bh & 3;

  __shared__ alignas(16) char smem[98304];   // Ks 48KB + Vs 48KB (3 buf); Olds aliased
  __shared__ float Llds[16][64];
  __shared__ float redl[64];
  __shared__ float fscl[32];
  __hip_bfloat16* KsB = (__hip_bfloat16*)smem;            // [4 jq][3 buf][2048]
  __hip_bfloat16* VsB = KsB + 24576;                      // [4 jq][3 buf][2048]
  float* Olds = (float*)smem;                             // [4 qsub][3][16*68] post-loop

  // ---- fused fsc: reduce ssp partials for this bh (rows 0..31 q, 32..63 k) ----
  if (tid < 512) {
    int row = tid >> 3, part = tid & 7;      // 64 rows x 8 parts
    int qk = row >> 5, r32 = row & 31;
    const float* pp = ssp + (size_t)((qk * 2 + b) * 128 + h * 32 + r32) * 64 + part * 8;
    float s = 0.f;
#pragma unroll
    for (int k = 0; k < 8; ++k) s += pp[k];
    s += __shfl_xor(s, 1);
    s += __shfl_xor(s, 2);
    s += __shfl_xor(s, 4);
    if (part == 0) redl[row] = s;
  }
  __syncthreads();
  if (tid < 32) {
    float vq = 1.f / fmaxf(sqrtf(redl[tid]), 0.1f);
    float vk = 1.f / fmaxf(sqrtf(redl[tid + 32]), 0.1f);
    fscl[tid] = vq * vk * QSCALE_LOG2E;
  }
  __syncthreads();

  const __hip_bfloat16* kg = Kt + (size_t)bh * NSP * DIMH;
  const __hip_bfloat16* vg = Vb + (size_t)bh * DIMH * NSP;

  // Q fragment: fp32 load, scale by fscl, pack to bf16 (single rounding)
  const float* qpf = Qf + ((size_t)bh * NSP + i0 + l31) * DIMH;
  s16x8 qb0, qb1;
  {
    f32x4 a0 = *(const f32x4*)(qpf + hi * 8);
    f32x4 a1 = *(const f32x4*)(qpf + hi * 8 + 4);
    f32x4 a2 = *(const f32x4*)(qpf + 16 + hi * 8);
    f32x4 a3 = *(const f32x4*)(qpf + 16 + hi * 8 + 4);
    f32x4 f0 = *(const f32x4*)(fscl + hi * 8);
    f32x4 f1 = *(const f32x4*)(fscl + hi * 8 + 4);
    f32x4 f2 = *(const f32x4*)(fscl + 16 + hi * 8);
    f32x4 f3 = *(const f32x4*)(fscl + 16 + hi * 8 + 4);
    union { unsigned u[4]; s16x8 v; } p0, p1;
    p0.u[0] = cvtpk_bf16(a0[0] * f0[0], a0[1] * f0[1]);
    p0.u[1] = cvtpk_bf16(a0[2] * f0[2], a0[3] * f0[3]);
    p0.u[2] = cvtpk_bf16(a1[0] * f1[0], a1[1] * f1[1]);
    p0.u[3] = cvtpk_bf16(a1[2] * f1[2], a1[3] * f1[3]);
    p1.u[0] = cvtpk_bf16(a2[0] * f2[0], a2[1] * f2[1]);
    p1.u[1] = cvtpk_bf16(a2[2] * f2[2], a2[3] * f2[3]);
    p1.u[2] = cvtpk_bf16(a3[0] * f3[0], a3[1] * f3[1]);
    p1.u[3] = cvtpk_bf16(a3[2] * f3[2], a3[3] * f3[3]);
    qb0 = p0.v; qb1 = p1.v;
  }
  // pin: all prologue global loads drained so vmcnt counts ONLY staging loads below
  asm volatile("s_waitcnt vmcnt(0)" ::: "memory");

  // stager: unit u = qsub*64+lane (256 units); LDS linear at u*16B within [jq][buf] tile.
  // K unit: row u>>2, slot u&3, src chunk (u&3)^((row+row>>2)&3).
  // V unit: row u>>3, slot u&7, src chunk (u&7)^((row+row>>3)&7).
  int ku = qsub * 64 + lane;
  int krow = ku >> 2;
  int kch = (ku & 3) ^ ((krow + (krow >> 2)) & 3);
  const __hip_bfloat16* ksrc0 = kg + (size_t)krow * DIMH + (kch << 3);
  int vd = ku >> 3;
  int vch = (ku & 7) ^ ((vd + (vd >> 3)) & 7);
  const __hip_bfloat16* vsrc0 = vg + (size_t)vd * NSP + (vch << 3);
  int lbase = qsub * 512;   // elems within Ks/Vs[jq][buf]

  f32x16 O = {};
  float ls0 = 0.f, ls1 = 0.f;

#define STAGE(j0, buf)                                                         \
  {                                                                            \
    glds16(ksrc0 + (size_t)(j0) * DIMH, &KsB[(jq * 3 + (buf)) * 2048 + lbase]);\
    glds16(vsrc0 + (j0),                &VsB[(jq * 3 + (buf)) * 2048 + lbase]);\
  }

  STAGE(jbase, 0);
  STAGE(jbase + 64, 1);
  asm volatile("s_waitcnt vmcnt(2)" ::: "memory");   // buf0 landed; buf1 in flight
  __syncthreads();

#pragma unroll 1
  for (int t = 0; t < 16; ++t) {
    int bufc = t % 3;
    if (t < 14) STAGE(jbase + (t + 2) * 64, (t + 2) % 3);
    const __hip_bfloat16* kbase = &KsB[(jq * 3 + bufc) * 2048];
    const __hip_bfloat16* vbase = &VsB[(jq * 3 + bufc) * 2048];
    attn_sub2(kbase, vbase, 0, l31, hi, qb0, qb1, O, ls0);
    attn_sub2(kbase, vbase, 1, l31, hi, qb0, qb1, O, ls1);
    if (t < 14) {
      asm volatile("s_waitcnt vmcnt(2)" ::: "memory");   // STAGE(t+1) landed
      asm volatile("s_barrier" ::: "memory");
    } else if (t < 15) {
      asm volatile("s_waitcnt vmcnt(0)" ::: "memory");   // STAGE(15) landed
      asm volatile("s_barrier" ::: "memory");
    }
  }
#undef STAGE

  // ---- merge 4 j-quarters (Olds aliases the staging; barrier-separated) ----
  float lsum = ls0 + ls1;
  float lw = lsum + __shfl_xor(lsum, 32);   // full row sum for q-row i = l31 (this jq)
  Llds[wave][lane] = lw;
  __syncthreads();                          // all staging reads complete
  if (jq) {
    float* od = Olds + (size_t)(qsub * 3 + (jq - 1)) * 1088;
#pragma unroll
    for (int r = 0; r < 16; ++r) od[r * 68 + lane] = O[r];
  }
  __syncthreads();
  if (jq == 0) {
    float ltot = lw + Llds[wave + 4][lane] + Llds[wave + 8][lane] + Llds[wave + 12][lane];
    if (hi == 0) Llds[wave][l31] = ltot;    // reindex by q-row (same-wave DS order)
    float* o0 = Olds + (size_t)(qsub * 3) * 1088;
    float* o1 = o0 + 1088;
    float* o2 = o1 + 1088;
#pragma unroll
    for (int r = 0; r < 16; ++r) {
      int i = (r & 3) + 8 * (r >> 2) + 4 * hi;
      float li = Llds[wave][i];
      float sum = O[r] + o0[r * 68 + lane] + o1[r * 68 + lane] + o2[r * 68 + lane];
      o0[r * 68 + lane] = sum / li;
    }
  }
  __syncthreads();
  // store: bf16 n-major. thread -> (qsub q2, row i, 4-channel group cp)
  {
    int q2 = tid >> 8;              // 0..3
    int i  = (tid >> 3) & 31;       // q-row within qsub tile
    int cp = tid & 7;               // 4 channels each
    int r  = (i & 3) | ((i >> 3) << 2);
    int h2 = (i >> 2) & 1;
    const float* o0 = Olds + (size_t)(q2 * 3) * 1088 + r * 68 + h2 * 32 + cp * 4;
    uint2 pv;
    pv.x = cvtpk_bf16(o0[0], o0[1]);
    pv.y = cvtpk_bf16(o0[2], o0[3]);
    __hip_bfloat16* dst = Otb + ((size_t)(b * NSP + qt * 128 + q2 * 32 + i)) * HID + h * 32 + cp * 4;
    *(uint2*)dst = pv;
  }
}

// ---------------- output projection on MFMA: out[o][n] = sum_c w[o][c]*Ot[n][c] + bias ----------------
__global__ __launch_bounds__(256, 4) void k_projm(const __hip_bfloat16* __restrict__ Otb,
                                                  const float* __restrict__ w,
                                                  const float* __restrict__ bias,
                                                  float* __restrict__ out) {
  int xcd = blockIdx.x & 7;
  int ot  = (blockIdx.x >> 3) & 3;
  int yy  = blockIdx.x >> 5;           // 0..7
  int tile = xcd * 8 + yy;             // 0..63, XCD-local Ot slice
  int n0 = tile * 128;
  int lane = threadIdx.x & 63, wave = threadIdx.x >> 6;
  int l31 = lane & 31, hi = lane >> 5;
  int orow = ot * 32 + l31;

  s16x8 wf[8];
  const float* wr = w + orow * HID + hi * 8;
#pragma unroll
  for (int k = 0; k < 8; ++k) {
    f32x4 a = *(const f32x4*)(wr + k * 16);
    f32x4 b2 = *(const f32x4*)(wr + k * 16 + 4);
    union { unsigned u[4]; s16x8 v; } p;
    p.u[0] = cvtpk_bf16(a[0], a[1]);
    p.u[1] = cvtpk_bf16(a[2], a[3]);
    p.u[2] = cvtpk_bf16(b2[0], b2[1]);
    p.u[3] = cvtpk_bf16(b2[2], b2[3]);
    wf[k] = p.v;
  }

  int nw = n0 + wave * 32;
  int b = nw >> 12, np = nw & 4095;
  const __hip_bfloat16* src = Otb + ((size_t)(b * NSP + np)) * HID;
  f32x16 acc = {};
#pragma unroll
  for (int k = 0; k < 8; ++k) {
    s16x8 bfr = *(const s16x8*)(src + (size_t)l31 * HID + k * 16 + hi * 8);
    acc = __builtin_amdgcn_mfma_f32_32x32x16_bf16(wf[k], bfr, acc, 0, 0, 0);
  }

  float* outb = out + (size_t)b * DIM * NSP + np + l31;
#pragma unroll
  for (int r2 = 0; r2 < 16; ++r2) {
    int o = ot * 32 + (r2 & 3) + 8 * (r2 >> 2) + 4 * hi;
    outb[(size_t)o * NSP] = acc[r2] + bias[o];
  }
}

extern "C" void kernel_launch(void* const* d_in, const int* in_sizes, int n_in,
                              void* d_out, int out_size, void* d_ws, size_t ws_size,
                              hipStream_t stream) {
  const float* x     = (const float*)d_in[0];
  const float* y     = (const float*)d_in[1];
  const float* w_qkv = (const float*)d_in[2];
  const float* w_out = (const float*)d_in[3];
  const float* b_out = (const float*)d_in[4];
  float* out = (float*)d_out;

  char* ws = (char*)d_ws;
  __hip_bfloat16* xt  = (__hip_bfloat16*)(ws);              // 2 MB
  __hip_bfloat16* yt  = (__hip_bfloat16*)(ws + (2  << 20)); // 2 MB
  float* Qf           = (float*)(ws + (4  << 20));          // 4 MB (fp32, unnormalized)
  __hip_bfloat16* Kr  = (__hip_bfloat16*)(ws + (8  << 20)); // 2 MB (bf16, unnormalized)
  __hip_bfloat16* Vb  = (__hip_bfloat16*)(ws + (10 << 20)); // 2 MB
  __hip_bfloat16* Otb = (__hip_bfloat16*)(ws + (12 << 20)); // 2 MB (bf16, n-major)
  float* ssp          = (float*)(ws + (16 << 20));          // 128 KB partial sums

  k_cvt   <<<256, 256,  0, stream>>>(x, y, xt, yt);
  k_qkvm  <<<384, 256,  0, stream>>>(xt, yt, w_qkv, ssp, Qf, Kr, Vb);
  k_attn  <<<256, 1024, 0, stream>>>(Qf, Kr, Vb, ssp, Otb);
  k_projm <<<256, 256,  0, stream>>>(Otb, w_out, b_out, out);
}

// Round 23
// 57.548 us; speedup vs baseline: 1.0906x; 1.0025x over previous
//
#include <hip/hip_runtime.h>
#include <hip/hip_bf16.h>

#define HEADS 4
#define DIMH  32
#define HID   128
#define DIM   128
#define NSP   4096
// 10 * log2(e); folded into the per-channel factor f = scq*sck*QSCALE_LOG2E.
#define QSCALE_LOG2E 14.426950408889634f

typedef __attribute__((ext_vector_type(4)))  float f32x4;
typedef __attribute__((ext_vector_type(16))) float f32x16;
typedef __attribute__((ext_vector_type(8)))  short s16x8;

__device__ __forceinline__ unsigned cvtpk_bf16(float a, float b) {
  unsigned d;
  asm("v_cvt_pk_bf16_f32 %0, %1, %2" : "=v"(d) : "v"(a), "v"(b));
  return d;
}

// ---------------- convert+transpose x,y fp32 [b][c][n] -> bf16 [b*n][c] ----------------
__global__ __launch_bounds__(256) void k_cvt(const float* __restrict__ x,
                                             const float* __restrict__ y,
                                             __hip_bfloat16* __restrict__ xt,
                                             __hip_bfloat16* __restrict__ yt) {
  int bid = blockIdx.x;          // 2 tensor * 2 b * 64 ntiles
  int t = bid >> 7, rem = bid & 127;
  int b = rem >> 6, nt = rem & 63;
  int n0 = nt * 64;
  const float* src = (t ? y : x) + (size_t)b * DIM * NSP;
  __hip_bfloat16* dst = (t ? yt : xt) + (size_t)b * NSP * DIM;

  __shared__ alignas(16) __hip_bfloat16 tile[64 * 136];
  int n = threadIdx.x & 63, c0 = threadIdx.x >> 6;   // c0 0..3
  const float* sp = src + n0 + n;
#pragma unroll
  for (int cc = 0; cc < 32; ++cc) {
    int c = cc * 4 + c0;
    tile[n * 136 + c] = __float2bfloat16(sp[(size_t)c * NSP]);
  }
  __syncthreads();
  int rrow = threadIdx.x >> 2, cb = (threadIdx.x & 3) * 32;
  __hip_bfloat16* op = dst + (size_t)(n0 + rrow) * DIM + cb;
  const __hip_bfloat16* ip = tile + rrow * 136 + cb;
#pragma unroll
  for (int k = 0; k < 4; ++k)
    *(s16x8*)(op + k * 8) = *(const s16x8*)(ip + k * 8);
}

// ---------------- QKV GEMM on MFMA ----------------
// orows 0..127 = Q (fp32 out), 128..255 = K (bf16), 256..383 = V (bf16).
// Sum-of-squares: deterministic per-wave partials into ssp[512][64] (no atomics).
__global__ __launch_bounds__(256, 4) void k_qkvm(const __hip_bfloat16* __restrict__ xt,
                                                 const __hip_bfloat16* __restrict__ yt,
                                                 const float* __restrict__ w,
                                                 float* __restrict__ ssp,
                                                 float* __restrict__ Qf,
                                                 __hip_bfloat16* __restrict__ Kr,
                                                 __hip_bfloat16* __restrict__ Vb) {
  int xcd = blockIdx.x & 7;
  int r = blockIdx.x >> 3;        // 0..47
  int ot = r >> 2;                // 0..11
  int nts = r & 3;
  int tile = xcd * 4 + nts;       // n-tile 0..31
  int n0 = tile * 256;
  int lane = threadIdx.x & 63, wave = threadIdx.x >> 6;
  int l31 = lane & 31, hi = lane >> 5;
  int orow = ot * 32 + l31;

  s16x8 wf[8];
  const float* wr = w + orow * DIM + hi * 8;
#pragma unroll
  for (int k = 0; k < 8; ++k) {
    f32x4 a = *(const f32x4*)(wr + k * 16);
    f32x4 b2 = *(const f32x4*)(wr + k * 16 + 4);
    union { unsigned u[4]; s16x8 v; } p;
    p.u[0] = cvtpk_bf16(a[0], a[1]);
    p.u[1] = cvtpk_bf16(a[2], a[3]);
    p.u[2] = cvtpk_bf16(b2[0], b2[1]);
    p.u[3] = cvtpk_bf16(b2[2], b2[3]);
    wf[k] = p.v;
  }

  const __hip_bfloat16* src = (ot < 4 ? xt : yt);
  int nw = n0 + wave * 64;
  f32x16 acc0 = {}, acc1 = {};
#pragma unroll
  for (int k = 0; k < 8; ++k) {
    s16x8 b0 = *(const s16x8*)(src + (size_t)(nw + l31) * DIM + k * 16 + hi * 8);
    s16x8 b1 = *(const s16x8*)(src + (size_t)(nw + 32 + l31) * DIM + k * 16 + hi * 8);
    acc0 = __builtin_amdgcn_mfma_f32_32x32x16_bf16(wf[k], b0, acc0, 0, 0, 0);
    acc1 = __builtin_amdgcn_mfma_f32_32x32x16_bf16(wf[k], b1, acc1, 0, 0, 0);
  }

  int b = nw >> 12;
  if (ot < 8) {
    int h = ot & 3;
    if (ot < 4) {
#pragma unroll
      for (int nt = 0; nt < 2; ++nt) {
        int np = (nw + nt * 32 + l31) & 4095;
        float* base = Qf + ((size_t)((b * HEADS + h) * NSP + np)) * DIMH;
        const f32x16& A = nt ? acc1 : acc0;
#pragma unroll
        for (int m = 0; m < 4; ++m) {
          f32x4 v = { A[4 * m], A[4 * m + 1], A[4 * m + 2], A[4 * m + 3] };
          *(f32x4*)(base + 8 * m + 4 * hi) = v;
        }
      }
    } else {
#pragma unroll
      for (int nt = 0; nt < 2; ++nt) {
        int np = (nw + nt * 32 + l31) & 4095;
        __hip_bfloat16* base = Kr + ((size_t)((b * HEADS + h) * NSP + np)) * DIMH;
        const f32x16& A = nt ? acc1 : acc0;
#pragma unroll
        for (int m = 0; m < 4; ++m) {
          uint2 p2;
          p2.x = cvtpk_bf16(A[4 * m], A[4 * m + 1]);
          p2.y = cvtpk_bf16(A[4 * m + 2], A[4 * m + 3]);
          *(uint2*)(base + 8 * m + 4 * hi) = p2;
        }
      }
    }
    float p[16];
#pragma unroll
    for (int r2 = 0; r2 < 16; ++r2) p[r2] = acc0[r2] * acc0[r2] + acc1[r2] * acc1[r2];
#pragma unroll
    for (int r2 = 0; r2 < 16; ++r2) {
#pragma unroll
      for (int m2 = 1; m2 < 32; m2 <<= 1) p[r2] += __shfl_xor(p[r2], m2);
    }
    if (l31 == 0) {
      int t = (ot < 4 ? 0 : 1);
      int widx = (tile & 15) * 4 + wave;              // 0..63
      int rbase = (t * 2 + b) * 128 + h * 32;
#pragma unroll
      for (int r2 = 0; r2 < 16; ++r2) {
        int row = (r2 & 3) + 8 * (r2 >> 2) + 4 * hi;
        ssp[(size_t)(rbase + row) * 64 + widx] = p[r2];
      }
    }
  } else {
    int h = ot - 8;
#pragma unroll
    for (int nt = 0; nt < 2; ++nt) {
      int np = (nw + nt * 32 + l31) & 4095;
      const f32x16& A = nt ? acc1 : acc0;
#pragma unroll
      for (int r2 = 0; r2 < 16; ++r2) {
        int d = (r2 & 3) + 8 * (r2 >> 2) + 4 * hi;
        Vb[((size_t)((b * HEADS + h) * DIMH + d)) * NSP + np] = __float2bfloat16(A[r2]);
      }
    }
  }
}

// ---------------- flash attention: 3-buffer counted-vmcnt pipeline, shared staging ----------------
__device__ __forceinline__ void glds16(const __hip_bfloat16* g, __hip_bfloat16* l) {
  __builtin_amdgcn_global_load_lds(
      (const __attribute__((address_space(1))) unsigned int*)(const void*)g,
      (__attribute__((address_space(3))) unsigned int*)(void*)l, 16, 0, 0);
}

// One 32(q-rows) x 32(j) subtile from shared LDS tiles.
// K: 64B rows, phase (row + row>>2)&3. V: 128B rows, phase (row + row>>3)&7.
// Both hit the b128 bank floor (no excess conflicts; verified R18: 33K).
__device__ __forceinline__ void attn_sub2(const __hip_bfloat16* kbase,
                                          const __hip_bfloat16* vbase,
                                          int s, int l31, int hi,
                                          s16x8 qb0, s16x8 qb1,
                                          f32x16& O, float& lsum) {
  int krx = (l31 + (l31 >> 2)) & 3;
  int vrx = (l31 + (l31 >> 3)) & 7;
  const __hip_bfloat16* krow = kbase + (s * 32 + l31) * DIMH;
  s16x8 kf0 = *(const s16x8*)(krow + (((hi) ^ krx) << 3));
  s16x8 kf1 = *(const s16x8*)(krow + (((2 + hi) ^ krx) << 3));
  f32x16 z = {};
  f32x16 sv = __builtin_amdgcn_mfma_f32_32x32x16_bf16(kf0, qb0, z, 0, 0, 0);
  sv        = __builtin_amdgcn_mfma_f32_32x32x16_bf16(kf1, qb1, sv, 0, 0, 0);
  float p[16];
#pragma unroll
  for (int r = 0; r < 16; ++r) p[r] = __builtin_amdgcn_exp2f(sv[r]);
  float t0 = 0.f, t1 = 0.f;
#pragma unroll
  for (int r = 0; r < 16; r += 2) { t0 += p[r]; t1 += p[r + 1]; }
  lsum += t0 + t1;
  unsigned wA[4], wB[4];
#pragma unroll
  for (int m = 0; m < 4; ++m) {
    wA[m] = cvtpk_bf16(p[4 * m], p[4 * m + 1]);
    wB[m] = cvtpk_bf16(p[4 * m + 2], p[4 * m + 3]);
  }
  const __hip_bfloat16* vrow = vbase + l31 * 64;
#define PV_CHUNK(c2, vfrag)                                                    \
  {                                                                            \
    unsigned a0 = wA[2 * (c2)], a1 = wA[2 * (c2) + 1];                         \
    unsigned b0 = wB[2 * (c2)], b1 = wB[2 * (c2) + 1];                         \
    asm("v_permlane32_swap_b32 %0, %1" : "+v"(a0), "+v"(a1));                  \
    asm("v_permlane32_swap_b32 %0, %1" : "+v"(b0), "+v"(b1));                  \
    union { unsigned u[4]; s16x8 v; } pa;                                      \
    pa.u[0] = a0; pa.u[1] = b0; pa.u[2] = a1; pa.u[3] = b1;                    \
    O = __builtin_amdgcn_mfma_f32_32x32x16_bf16(pa.v, vfrag, O, 0, 0, 0);      \
  }
#pragma unroll
  for (int c2 = 0; c2 < 2; ++c2) {
    int cc = s * 2 + c2;
    s16x8 vf = *(const s16x8*)(vrow + (((cc * 2 + hi) ^ vrx) << 3));
    PV_CHUNK(c2, vf);
  }
#undef PV_CHUNK
}

// 16 waves (4 qsub x 4 jq), 128 q-rows x full j; grid 256 (8 bh XCD-local x 32 qt).
// TRIPLE-buffered shared staging with counted vmcnt(2) + raw s_barrier:
// loads stay in flight across barriers (T4); no drain-to-0 in the main loop.
__global__ __launch_bounds__(1024, 4) void k_attn(const float* __restrict__ Qf,
                                                  const __hip_bfloat16* __restrict__ Kt,
                                                  const __hip_bfloat16* __restrict__ Vb,
                                                  const float* __restrict__ ssp,
                                                  __hip_bfloat16* __restrict__ Otb) {
  int bh = blockIdx.x & 7, qt = blockIdx.x >> 3;   // 8 bh x 32 qt
  int tid = threadIdx.x, lane = tid & 63, wave = tid >> 6;
  int qsub = wave & 3, jq = wave >> 2;
  int l31 = lane & 31, hi = lane >> 5;
  int i0 = qt * 128 + qsub * 32;
  int jbase = jq * 1024;
  int b = bh >> 2, h = bh & 3;

  __shared__ alignas(16) char smem[98304];   // Ks 48KB + Vs 48KB (3 buf); Olds aliased
  __shared__ float Llds[16][64];
  __shared__ float redl[64];
  __shared__ float fscl[32];
  __hip_bfloat16* KsB = (__hip_bfloat16*)smem;            // [4 jq][3 buf][2048]
  __hip_bfloat16* VsB = KsB + 24576;                      // [4 jq][3 buf][2048]
  float* Olds = (float*)smem;                             // [4 qsub][3][16*68] post-loop

  // ---- fused fsc: reduce ssp partials for this bh (rows 0..31 q, 32..63 k) ----
  if (tid < 512) {
    int row = tid >> 3, part = tid & 7;      // 64 rows x 8 parts
    int qk = row >> 5, r32 = row & 31;
    const float* pp = ssp + (size_t)((qk * 2 + b) * 128 + h * 32 + r32) * 64 + part * 8;
    float s = 0.f;
#pragma unroll
    for (int k = 0; k < 8; ++k) s += pp[k];
    s += __shfl_xor(s, 1);
    s += __shfl_xor(s, 2);
    s += __shfl_xor(s, 4);
    if (part == 0) redl[row] = s;
  }
  __syncthreads();
  if (tid < 32) {
    float vq = 1.f / fmaxf(sqrtf(redl[tid]), 0.1f);
    float vk = 1.f / fmaxf(sqrtf(redl[tid + 32]), 0.1f);
    fscl[tid] = vq * vk * QSCALE_LOG2E;
  }
  __syncthreads();

  const __hip_bfloat16* kg = Kt + (size_t)bh * NSP * DIMH;
  const __hip_bfloat16* vg = Vb + (size_t)bh * DIMH * NSP;

  // Q fragment: fp32 load, scale by fscl, pack to bf16 (single rounding)
  const float* qpf = Qf + ((size_t)bh * NSP + i0 + l31) * DIMH;
  s16x8 qb0, qb1;
  {
    f32x4 a0 = *(const f32x4*)(qpf + hi * 8);
    f32x4 a1 = *(const f32x4*)(qpf + hi * 8 + 4);
    f32x4 a2 = *(const f32x4*)(qpf + 16 + hi * 8);
    f32x4 a3 = *(const f32x4*)(qpf + 16 + hi * 8 + 4);
    f32x4 f0 = *(const f32x4*)(fscl + hi * 8);
    f32x4 f1 = *(const f32x4*)(fscl + hi * 8 + 4);
    f32x4 f2 = *(const f32x4*)(fscl + 16 + hi * 8);
    f32x4 f3 = *(const f32x4*)(fscl + 16 + hi * 8 + 4);
    union { unsigned u[4]; s16x8 v; } p0, p1;
    p0.u[0] = cvtpk_bf16(a0[0] * f0[0], a0[1] * f0[1]);
    p0.u[1] = cvtpk_bf16(a0[2] * f0[2], a0[3] * f0[3]);
    p0.u[2] = cvtpk_bf16(a1[0] * f1[0], a1[1] * f1[1]);
    p0.u[3] = cvtpk_bf16(a1[2] * f1[2], a1[3] * f1[3]);
    p1.u[0] = cvtpk_bf16(a2[0] * f2[0], a2[1] * f2[1]);
    p1.u[1] = cvtpk_bf16(a2[2] * f2[2], a2[3] * f2[3]);
    p1.u[2] = cvtpk_bf16(a3[0] * f3[0], a3[1] * f3[1]);
    p1.u[3] = cvtpk_bf16(a3[2] * f3[2], a3[3] * f3[3]);
    qb0 = p0.v; qb1 = p1.v;
  }
  // pin: all prologue global loads drained so vmcnt counts ONLY staging loads below
  asm volatile("s_waitcnt vmcnt(0)" ::: "memory");

  // stager: unit u = qsub*64+lane (256 units); LDS linear at u*16B within [jq][buf].
  int ku = qsub * 64 + lane;
  int krow = ku >> 2;
  int kch = (ku & 3) ^ ((krow + (krow >> 2)) & 3);
  const __hip_bfloat16* ksrc0 = kg + (size_t)krow * DIMH + (kch << 3);
  int vd = ku >> 3;
  int vch = (ku & 7) ^ ((vd + (vd >> 3)) & 7);
  const __hip_bfloat16* vsrc0 = vg + (size_t)vd * NSP + (vch << 3);
  int lbase = qsub * 512;   // elems within Ks/Vs[jq][buf]

  f32x16 O = {};
  float ls0 = 0.f, ls1 = 0.f;

#define STAGE(j0, buf)                                                         \
  {                                                                            \
    glds16(ksrc0 + (size_t)(j0) * DIMH, &KsB[(jq * 3 + (buf)) * 2048 + lbase]);\
    glds16(vsrc0 + (j0),                &VsB[(jq * 3 + (buf)) * 2048 + lbase]);\
  }

  STAGE(jbase, 0);
  STAGE(jbase + 64, 1);
  asm volatile("s_waitcnt vmcnt(2)" ::: "memory");   // buf0 landed; buf1 in flight
  __syncthreads();

#pragma unroll 1
  for (int t = 0; t < 16; ++t) {
    int bufc = t % 3;
    if (t < 14) STAGE(jbase + (t + 2) * 64, (t + 2) % 3);
    const __hip_bfloat16* kbase = &KsB[(jq * 3 + bufc) * 2048];
    const __hip_bfloat16* vbase = &VsB[(jq * 3 + bufc) * 2048];
    attn_sub2(kbase, vbase, 0, l31, hi, qb0, qb1, O, ls0);
    attn_sub2(kbase, vbase, 1, l31, hi, qb0, qb1, O, ls1);
    if (t < 14) {
      asm volatile("s_waitcnt vmcnt(2)" ::: "memory");   // STAGE(t+1) landed
      asm volatile("s_barrier" ::: "memory");
    } else if (t < 15) {
      asm volatile("s_waitcnt vmcnt(0)" ::: "memory");   // STAGE(15) landed
      asm volatile("s_barrier" ::: "memory");
    }
  }
#undef STAGE

  // ---- merge 4 j-quarters (Olds aliases the staging; barrier-separated) ----
  float lsum = ls0 + ls1;
  float lw = lsum + __shfl_xor(lsum, 32);   // full row sum for q-row i = l31 (this jq)
  Llds[wave][lane] = lw;
  __syncthreads();                          // all staging reads complete
  if (jq) {
    float* od = Olds + (size_t)(qsub * 3 + (jq - 1)) * 1088;
#pragma unroll
    for (int r = 0; r < 16; ++r) od[r * 68 + lane] = O[r];
  }
  __syncthreads();
  if (jq == 0) {
    float ltot = lw + Llds[wave + 4][lane] + Llds[wave + 8][lane] + Llds[wave + 12][lane];
    if (hi == 0) Llds[wave][l31] = ltot;    // reindex by q-row (same-wave DS order)
    float* o0 = Olds + (size_t)(qsub * 3) * 1088;
    float* o1 = o0 + 1088;
    float* o2 = o1 + 1088;
#pragma unroll
    for (int r = 0; r < 16; ++r) {
      int i = (r & 3) + 8 * (r >> 2) + 4 * hi;
      float li = Llds[wave][i];
      float sum = O[r] + o0[r * 68 + lane] + o1[r * 68 + lane] + o2[r * 68 + lane];
      o0[r * 68 + lane] = sum / li;
    }
  }
  __syncthreads();
  // store: bf16 n-major. thread -> (qsub q2, row i, 4-channel group cp)
  {
    int q2 = tid >> 8;              // 0..3
    int i  = (tid >> 3) & 31;       // q-row within qsub tile
    int cp = tid & 7;               // 4 channels each
    int r  = (i & 3) | ((i >> 3) << 2);
    int h2 = (i >> 2) & 1;
    const float* o0 = Olds + (size_t)(q2 * 3) * 1088 + r * 68 + h2 * 32 + cp * 4;
    uint2 pv;
    pv.x = cvtpk_bf16(o0[0], o0[1]);
    pv.y = cvtpk_bf16(o0[2], o0[3]);
    __hip_bfloat16* dst = Otb + ((size_t)(b * NSP + qt * 128 + q2 * 32 + i)) * HID + h * 32 + cp * 4;
    *(uint2*)dst = pv;
  }
}

// ---------------- output projection on MFMA: out[o][n] = sum_c w[o][c]*Ot[n][c] + bias ----------------
__global__ __launch_bounds__(256, 4) void k_projm(const __hip_bfloat16* __restrict__ Otb,
                                                  const float* __restrict__ w,
                                                  const float* __restrict__ bias,
                                                  float* __restrict__ out) {
  int xcd = blockIdx.x & 7;
  int ot  = (blockIdx.x >> 3) & 3;
  int yy  = blockIdx.x >> 5;           // 0..7
  int tile = xcd * 8 + yy;             // 0..63, XCD-local Ot slice
  int n0 = tile * 128;
  int lane = threadIdx.x & 63, wave = threadIdx.x >> 6;
  int l31 = lane & 31, hi = lane >> 5;
  int orow = ot * 32 + l31;

  s16x8 wf[8];
  const float* wr = w + orow * HID + hi * 8;
#pragma unroll
  for (int k = 0; k < 8; ++k) {
    f32x4 a = *(const f32x4*)(wr + k * 16);
    f32x4 b2 = *(const f32x4*)(wr + k * 16 + 4);
    union { unsigned u[4]; s16x8 v; } p;
    p.u[0] = cvtpk_bf16(a[0], a[1]);
    p.u[1] = cvtpk_bf16(a[2], a[3]);
    p.u[2] = cvtpk_bf16(b2[0], b2[1]);
    p.u[3] = cvtpk_bf16(b2[2], b2[3]);
    wf[k] = p.v;
  }

  int nw = n0 + wave * 32;
  int b = nw >> 12, np = nw & 4095;
  const __hip_bfloat16* src = Otb + ((size_t)(b * NSP + np)) * HID;
  f32x16 acc = {};
#pragma unroll
  for (int k = 0; k < 8; ++k) {
    s16x8 bfr = *(const s16x8*)(src + (size_t)l31 * HID + k * 16 + hi * 8);
    acc = __builtin_amdgcn_mfma_f32_32x32x16_bf16(wf[k], bfr, acc, 0, 0, 0);
  }

  float* outb = out + (size_t)b * DIM * NSP + np + l31;
#pragma unroll
  for (int r2 = 0; r2 < 16; ++r2) {
    int o = ot * 32 + (r2 & 3) + 8 * (r2 >> 2) + 4 * hi;
    outb[(size_t)o * NSP] = acc[r2] + bias[o];
  }
}

extern "C" void kernel_launch(void* const* d_in, const int* in_sizes, int n_in,
                              void* d_out, int out_size, void* d_ws, size_t ws_size,
                              hipStream_t stream) {
  const float* x     = (const float*)d_in[0];
  const float* y     = (const float*)d_in[1];
  const float* w_qkv = (const float*)d_in[2];
  const float* w_out = (const float*)d_in[3];
  const float* b_out = (const float*)d_in[4];
  float* out = (float*)d_out;

  char* ws = (char*)d_ws;
  __hip_bfloat16* xt  = (__hip_bfloat16*)(ws);              // 2 MB
  __hip_bfloat16* yt  = (__hip_bfloat16*)(ws + (2  << 20)); // 2 MB
  float* Qf           = (float*)(ws + (4  << 20));          // 4 MB (fp32, unnormalized)
  __hip_bfloat16* Kr  = (__hip_bfloat16*)(ws + (8  << 20)); // 2 MB (bf16, unnormalized)
  __hip_bfloat16* Vb  = (__hip_bfloat16*)(ws + (10 << 20)); // 2 MB
  __hip_bfloat16* Otb = (__hip_bfloat16*)(ws + (12 << 20)); // 2 MB (bf16, n-major)
  float* ssp          = (float*)(ws + (16 << 20));          // 128 KB partial sums

  k_cvt   <<<256, 256,  0, stream>>>(x, y, xt, yt);
  k_qkvm  <<<384, 256,  0, stream>>>(xt, yt, w_qkv, ssp, Qf, Kr, Vb);
  k_attn  <<<256, 1024, 0, stream>>>(Qf, Kr, Vb, ssp, Otb);
  k_projm <<<256, 256,  0, stream>>>(Otb, w_out, b_out, out);
}